// Round 3
// baseline (550.627 us; speedup 1.0000x reference)
//
#include <hip/hip_runtime.h>

typedef unsigned int u32;
typedef unsigned long long u64;
typedef _Float16 f16;
typedef __attribute__((ext_vector_type(4))) _Float16 f16x4;
typedef __attribute__((ext_vector_type(8))) _Float16 f16x8;
typedef __attribute__((ext_vector_type(4))) float f32x4;
typedef const __attribute__((address_space(1))) void* gp_t;
typedef __attribute__((address_space(3))) void* lp_t;

#define TSEQ 2048

// monotone fp32 -> u32 map (order-preserving)
__device__ __forceinline__ u32 f2sort(float f) {
  u32 u = __float_as_uint(f);
  return u ^ ((u32)((int)u >> 31) | 0x80000000u);
}
__device__ __forceinline__ float sort2f(u32 u) {
  u ^= (u & 0x80000000u) ? 0x80000000u : 0xFFFFFFFFu;
  return __uint_as_float(u);
}

__device__ __forceinline__ void glds16(const f16* g, f16* l) {
  __builtin_amdgcn_global_load_lds((gp_t)g, (lp_t)l, 16, 0, 0);
}

__device__ __forceinline__ u32 umax2(u32 a, u32 b) { return a > b ? a : b; }

// max across each 16-lane DPP row via rotate-reduce (row_ror 8/4/2/1).
// All 16 lanes end with the row max; DPP-only, no LDS op on the chain.
__device__ __forceinline__ u32 dppmax16(u32 v) {
  u32 t;
  t = (u32)__builtin_amdgcn_update_dpp(0, (int)v, 0x128, 0xF, 0xF, true);
  v = v > t ? v : t;
  t = (u32)__builtin_amdgcn_update_dpp(0, (int)v, 0x124, 0xF, 0xF, true);
  v = v > t ? v : t;
  t = (u32)__builtin_amdgcn_update_dpp(0, (int)v, 0x122, 0xF, 0xF, true);
  v = v > t ? v : t;
  t = (u32)__builtin_amdgcn_update_dpp(0, (int)v, 0x121, 0xF, 0xF, true);
  v = v > t ? v : t;
  return v;
}
// sum across each 16-lane row via rotate-reduce, result in all 16 lanes
__device__ __forceinline__ float dppsum16(float v) {
  float t;
  t = __int_as_float(
      __builtin_amdgcn_update_dpp(0, __float_as_int(v), 0x128, 0xF, 0xF, true));
  v += t;
  t = __int_as_float(
      __builtin_amdgcn_update_dpp(0, __float_as_int(v), 0x124, 0xF, 0xF, true));
  v += t;
  t = __int_as_float(
      __builtin_amdgcn_update_dpp(0, __float_as_int(v), 0x122, 0xF, 0xF, true));
  v += t;
  t = __int_as_float(
      __builtin_amdgcn_update_dpp(0, __float_as_int(v), 0x121, 0xF, 0xF, true));
  v += t;
  return v;
}

// depth-4 tree max over 16 registers
__device__ __forceinline__ u32 tree16(const u32* k) {
  u32 t0 = umax2(k[0], k[1]), t1 = umax2(k[2], k[3]);
  u32 t2 = umax2(k[4], k[5]), t3 = umax2(k[6], k[7]);
  u32 t4 = umax2(k[8], k[9]), t5 = umax2(k[10], k[11]);
  u32 t6 = umax2(k[12], k[13]), t7 = umax2(k[14], k[15]);
  t0 = umax2(t0, t1); t2 = umax2(t2, t3);
  t4 = umax2(t4, t5); t6 = umax2(t6, t7);
  return umax2(umax2(t0, t2), umax2(t4, t6));
}

// ---------------------------------------------------------------------------
// fp32 -> f16: x (1048576 f4), Wq (524288), Wo (262144), keys (131072).
// values stay fp32 (gathered directly). grid = 7680 blocks exactly.
// ---------------------------------------------------------------------------
__global__ __launch_bounds__(256) void cvt_all(
    const float* __restrict__ x, const float* __restrict__ wq,
    const float* __restrict__ wo, const float* __restrict__ ky,
    f16* __restrict__ xd, f16* __restrict__ wqd, f16* __restrict__ wod,
    f16* __restrict__ kyd) {
  int g = blockIdx.x * 256 + threadIdx.x;
  const float* s;
  f16* d;
  int off;
  if (g < 1048576)      { s = x;  d = xd;  off = g; }
  else if (g < 1572864) { s = wq; d = wqd; off = g - 1048576; }
  else if (g < 1835008) { s = wo; d = wod; off = g - 1572864; }
  else                  { s = ky; d = kyd; off = g - 1835008; }
  float4 v = ((const float4*)s)[off];
  f16x4 o;
  o[0] = (f16)v.x; o[1] = (f16)v.y; o[2] = (f16)v.z; o[3] = (f16)v.w;
  ((f16x4*)d)[off] = o;
}

// ---------------------------------------------------------------------------
// m97-style f16 NT GEMM: C[m,n] = sum_k A[m,k]*B[n,k] (+bias), A/B f16,
// C fp32 or f16. 128xBN tile (BN=128 or 64), BK=32, global_load_lds w=16.
// ---------------------------------------------------------------------------
template <int BN>
__global__ __launch_bounds__(256) void gemm_f16(
    const f16* __restrict__ A, int lda, const f16* __restrict__ B, int ldb,
    const float* __restrict__ bias, void* __restrict__ Cv, int ldc, int K,
    int c_f16) {
  constexpr int NJ = BN / 32;
  __shared__ f16 As[128 * 32];
  __shared__ f16 Bs[BN * 32];
  const int tid = threadIdx.x;
  const int lane = tid & 63, wave = tid >> 6;
  const int m0 = blockIdx.y << 7, n0 = blockIdx.x * BN;
  const int c0 = wave * 128 + lane, c1 = c0 + 64;
  const int r0 = c0 >> 2, s0 = c0 & 3;
  const int r1 = c1 >> 2, s1 = c1 & 3;
  const int cB = wave * 64 + lane;          // BN=64 B-staging index
  const int rB = cB >> 2, sB = cB & 3;
  const f16* Ab = A + (size_t)m0 * lda;
  const f16* Bb = B + (size_t)n0 * ldb;
  const int fm = lane & 15, fq = lane >> 4, fk = fq << 3;
  const int wm = (wave >> 1) << 6, wn = (wave & 1) * (BN / 2);
  f32x4 acc[4][NJ] = {};
  for (int k0 = 0; k0 < K; k0 += 32) {
    __syncthreads();
    glds16(Ab + (size_t)r0 * lda + k0 + s0 * 8, As + (size_t)c0 * 8 - lane * 8);
    glds16(Ab + (size_t)r1 * lda + k0 + s1 * 8, As + (size_t)c1 * 8 - lane * 8);
    if constexpr (BN == 128) {
      glds16(Bb + (size_t)r0 * ldb + k0 + s0 * 8,
             Bs + (size_t)c0 * 8 - lane * 8);
      glds16(Bb + (size_t)r1 * ldb + k0 + s1 * 8,
             Bs + (size_t)c1 * 8 - lane * 8);
    } else {
      glds16(Bb + (size_t)rB * ldb + k0 + sB * 8,
             Bs + (size_t)cB * 8 - lane * 8);
    }
    __syncthreads();
    f16x8 af[4], bf[NJ];
#pragma unroll
    for (int mi = 0; mi < 4; mi++)
      af[mi] = *(const f16x8*)&As[(wm + mi * 16 + fm) * 32 + fk];
#pragma unroll
    for (int nj = 0; nj < NJ; nj++)
      bf[nj] = *(const f16x8*)&Bs[(wn + nj * 16 + fm) * 32 + fk];
#pragma unroll
    for (int mi = 0; mi < 4; mi++)
#pragma unroll
      for (int nj = 0; nj < NJ; nj++)
        acc[mi][nj] = __builtin_amdgcn_mfma_f32_16x16x32_f16(
            af[mi], bf[nj], acc[mi][nj], 0, 0, 0);
  }
  if (c_f16) {
    f16* C = (f16*)Cv;
#pragma unroll
    for (int mi = 0; mi < 4; mi++)
#pragma unroll
      for (int r = 0; r < 4; r++) {
        int row = m0 + wm + mi * 16 + fq * 4 + r;
        f16* cp = C + (size_t)row * ldc + n0 + wn + fm;
#pragma unroll
        for (int nj = 0; nj < NJ; nj++) cp[nj * 16] = (f16)acc[mi][nj][r];
      }
  } else {
    float* C = (float*)Cv;
    float bb[NJ];
#pragma unroll
    for (int nj = 0; nj < NJ; nj++)
      bb[nj] = bias ? bias[n0 + wn + nj * 16 + fm] : 0.f;
#pragma unroll
    for (int mi = 0; mi < 4; mi++)
#pragma unroll
      for (int r = 0; r < 4; r++) {
        int row = m0 + wm + mi * 16 + fq * 4 + r;
        float* cp = C + (size_t)row * ldc + n0 + wn + fm;
#pragma unroll
        for (int nj = 0; nj < NJ; nj++) cp[nj * 16] = acc[mi][nj][r] + bb[nj];
      }
  }
}

// ---------------------------------------------------------------------------
// FUSED Q-projection + dots + stage-1 top-32.
// Phase A: per-block 64x128x1024 GEMM computes the Q column-slice this z
//   needs (the 16 z-slices partition Q's columns -> each Q element computed
//   exactly once; gemm1 + Qf round-trip eliminated). Result -> LDS f16 in
//   4 BK=32 panels (same [row][32] layout as before; avoids [row][128]
//   bank conflicts).
// Phase B: dots 64x256x128, A from LDS panels, keys read DIRECTLY from L2
//   (64 KB slice, re-read by 64 blocks; LDS-staging it was pure overhead).
//   No barriers in this phase.
// Phase C: DPP top-32 selection, paired rows (2 independent chains).
// Co-resident blocks sit in different phases -> selection VALU overlaps
// other blocks' MFMA on the same CU.
// ---------------------------------------------------------------------------
__global__ __launch_bounds__(256) void qdots_topk1(
    const f16* __restrict__ xf,     // (4096,1024)
    const f16* __restrict__ wqf,    // (2048,1024)
    const f16* __restrict__ keysf,  // (8,256,2,128)
    float* __restrict__ s1s, int* __restrict__ s1i) {
  __shared__ f16 Axs[64 * 64];       // 8 KB  x tile (BK=64)
  __shared__ f16 Bws[128 * 64];      // 16 KB Wq tile (BK=64)
  __shared__ f16 Qs[4][64 * 32];     // 16 KB Q slice, 4 BK=32 panels
  const int tid = threadIdx.x;
  const int lane = tid & 63, wave = tid >> 6;
  const int z = blockIdx.x;  // h*2+p
  const int h = z >> 1, p = z & 1;
  const int m0 = blockIdx.y << 6;
  const int nbase = p * 1024 + h * 128;
  const int fm = lane & 15, fq = lane >> 4, fk = fq << 3;
  // ---------------- Phase A: Q slice GEMM (64x128, K=1024, BK=64) ---------
  f32x4 accQ[8] = {};
  for (int k0 = 0; k0 < 1024; k0 += 64) {
    __syncthreads();
    {
      int c = tid;  // x tile: 64 rows x 64 k, 512 chunks, 2/thread
      glds16(xf + (size_t)(m0 + (c >> 3)) * 1024 + k0 + (c & 7) * 8,
             Axs + (size_t)c * 8 - lane * 8);
      c = tid + 256;
      glds16(xf + (size_t)(m0 + (c >> 3)) * 1024 + k0 + (c & 7) * 8,
             Axs + (size_t)c * 8 - lane * 8);
    }
#pragma unroll
    for (int q = 0; q < 4; q++) {  // Wq tile: 128 rows x 64 k, 4/thread
      int c = tid + 256 * q;
      glds16(wqf + (size_t)(nbase + (c >> 3)) * 1024 + k0 + (c & 7) * 8,
             Bws + (size_t)c * 8 - lane * 8);
    }
    __syncthreads();
#pragma unroll
    for (int s = 0; s < 2; s++) {
      f16x8 af = *(const f16x8*)&Axs[(wave * 16 + fm) * 64 + s * 32 + fk];
#pragma unroll
      for (int j = 0; j < 8; j++) {
        f16x8 bw = *(const f16x8*)&Bws[(j * 16 + fm) * 64 + s * 32 + fk];
        accQ[j] =
            __builtin_amdgcn_mfma_f32_16x16x32_f16(af, bw, accQ[j], 0, 0, 0);
      }
    }
  }
  // write Q slice to LDS panels: C elem (row=wave*16+fq*4+r, d=j*16+fm)
#pragma unroll
  for (int j = 0; j < 8; j++) {
    int pn = j >> 1;
    int kk = (j & 1) * 16 + fm;
#pragma unroll
    for (int r = 0; r < 4; r++)
      Qs[pn][(wave * 16 + fq * 4 + r) * 32 + kk] = (f16)accQ[j][r];
  }
  __syncthreads();
  // ---------------- Phase B: dots 64x256x128, keys direct from L2 ---------
  const f16* Bk = keysf + ((size_t)h * 512 + p) * 128;  // row stride 256 f16
  f32x4 acc[16] = {};
#pragma unroll
  for (int k0 = 0; k0 < 128; k0 += 32) {
    f16x8 af = *(const f16x8*)&Qs[k0 >> 5][(wave * 16 + fm) * 32 + fk];
#pragma unroll
    for (int j = 0; j < 16; j++) {
      f16x8 bf = *(const f16x8*)&Bk[(size_t)(j * 16 + fm) * 256 + k0 + fk];
      acc[j] = __builtin_amdgcn_mfma_f32_16x16x32_f16(af, bf, acc[j], 0, 0, 0);
    }
  }
  // ---------------- Phase C: top-32 per row (paired chains) ---------------
#pragma unroll
  for (int rp = 0; rp < 2; rp++) {
    u32 keyA[16], keyB[16];
#pragma unroll
    for (int j = 0; j < 16; j++) {
      keyA[j] = (f2sort(acc[j][2 * rp]) & ~0xFFu) | (u32)((j << 4) | fm);
      keyB[j] = (f2sort(acc[j][2 * rp + 1]) & ~0xFFu) | (u32)((j << 4) | fm);
    }
    u32 g0A = 0, g1A = 0, g0B = 0, g1B = 0;
    for (int it = 0; it < 32; it++) {
      u32 lmA = tree16(keyA);
      u32 lmB = tree16(keyB);
      u32 gmA = dppmax16(lmA);
      u32 gmB = dppmax16(lmB);
#pragma unroll
      for (int j = 0; j < 16; j++) {
        keyA[j] = (keyA[j] == gmA) ? 0u : keyA[j];
        keyB[j] = (keyB[j] == gmB) ? 0u : keyB[j];
      }
      bool sel = (fm == (it & 15));
      if (it < 16) {
        g0A = sel ? gmA : g0A;
        g0B = sel ? gmB : g0B;
      } else {
        g1A = sel ? gmA : g1A;
        g1B = sel ? gmB : g1B;
      }
    }
    int mA = m0 + wave * 16 + (fq << 2) + 2 * rp;
    int bA = mA >> 11, tA = mA & 2047;
    size_t orowA = ((((size_t)(bA * 8 + h)) * TSEQ + tA) * 2 + p) * 32;
    s1s[orowA + fm] = sort2f(g0A & ~0xFFu);
    s1s[orowA + fm + 16] = sort2f(g1A & ~0xFFu);
    s1i[orowA + fm] = (int)(g0A & 0xFFu);  // n = (slot<<4)|lane
    s1i[orowA + fm + 16] = (int)(g1A & 0xFFu);
    int mB = mA + 1;
    int bB = mB >> 11, tB = mB & 2047;
    size_t orowB = ((((size_t)(bB * 8 + h)) * TSEQ + tB) * 2 + p) * 32;
    s1s[orowB + fm] = sort2f(g0B & ~0xFFu);
    s1s[orowB + fm + 16] = sort2f(g1B & ~0xFFu);
    s1i[orowB + fm] = (int)(g0B & 0xFFu);
    s1i[orowB + fm + 16] = (int)(g1B & 0xFFu);
  }
}

// ---------------------------------------------------------------------------
// Stage-2: combine halves, top-32 of 32x32 sum grid via dominance frontier
// ((i+1)(j+1)<=32 -> 119 candidates), DPP selection, softmax, fp32 value
// gather straight from the input table (~L3-resident), weighted sum -> f16.
// ---------------------------------------------------------------------------
__global__ __launch_bounds__(256) void topk2_gather(
    const float* __restrict__ s1s, const int* __restrict__ s1i,
    const float* __restrict__ valf, f16* __restrict__ headout) {
  __shared__ unsigned short cand[128];  // (i<<5)|j, 0xFFFF = pad
  __shared__ float s0sh[16][32];
  __shared__ float s1sh[16][32];
  __shared__ int i0sh[16][32];
  __shared__ int i1sh[16][32];
  __shared__ int vtab[16][32];
  __shared__ float wtab[16][32];
  const int tid = threadIdx.x;
  if (tid < 128) {
    int c = tid;
    unsigned short enc = 0xFFFF;
    if (c < 119) {
      int rem = c, i = 0;
      for (i = 0; i < 32; i++) {
        int cnt = 32 / (i + 1);
        if (rem < cnt) break;
        rem -= cnt;
      }
      enc = (unsigned short)((i << 5) | rem);
    }
    cand[tid] = enc;
  }
  const int rloc = tid >> 4;
  const int l = tid & 15;
  const int row = blockIdx.x * 16 + rloc;  // (b,h,t)
  const int b = row >> 14;
  const int h = (row >> 11) & 7;
  const int t = row & 2047;
  const int tt = t >> 1, p = t & 1;
  size_t rbase = (size_t)(b * 8 + h) * TSEQ;
  size_t base0 = ((rbase + tt) * 2 + p) * 32;
  size_t base1 = ((rbase + tt + 1024) * 2 + p) * 32;
  s0sh[rloc][l] = s1s[base0 + l];
  s0sh[rloc][l + 16] = s1s[base0 + l + 16];
  s1sh[rloc][l] = s1s[base1 + l];
  s1sh[rloc][l + 16] = s1s[base1 + l + 16];
  i0sh[rloc][l] = s1i[base0 + l];
  i0sh[rloc][l + 16] = s1i[base0 + l + 16];
  i1sh[rloc][l] = s1i[base1 + l];
  i1sh[rloc][l + 16] = s1i[base1 + l + 16];
  __syncthreads();
  u32 key[8];
#pragma unroll
  for (int s = 0; s < 8; s++) {
    int c = l + 16 * s;  // == (s<<4)|l
    unsigned short e = cand[c];
    u32 kk = 0u;
    if (e != 0xFFFF) {
      float v = s0sh[rloc][e >> 5] + s1sh[rloc][e & 31];
      kk = (f2sort(v) & ~0xFFu) | (u32)c;
    }
    key[s] = kk;
  }
  u32 g0 = 0, g1 = 0;
  for (int it = 0; it < 32; it++) {
    // depth-3 tree max over the 8 local keys
    u32 t0 = umax2(key[0], key[1]), t1 = umax2(key[2], key[3]);
    u32 t2 = umax2(key[4], key[5]), t3 = umax2(key[6], key[7]);
    u32 lm = umax2(umax2(t0, t1), umax2(t2, t3));
    u32 gm = dppmax16(lm);
#pragma unroll
    for (int s = 0; s < 8; s++) key[s] = (key[s] == gm) ? 0u : key[s];
    bool sel = (l == (it & 15));
    if (it < 16) g0 = sel ? gm : g0;
    else         g1 = sel ? gm : g1;
  }
  // decode winners (lane l holds winners l and l+16, descending order)
  float sc0 = sort2f(g0 & ~0xFFu);
  float sc1 = sort2f(g1 & ~0xFFu);
  unsigned short e0c = cand[g0 & 0xFFu];
  unsigned short e1c = cand[g1 & 0xFFu];
  int vidx0 = i0sh[rloc][e0c >> 5] * 256 + i1sh[rloc][e0c & 31];
  int vidx1 = i0sh[rloc][e1c >> 5] * 256 + i1sh[rloc][e1c & 31];
  // softmax: winner 0 (group lane 0) is the max
  float mx = __int_as_float(
      __builtin_amdgcn_ds_swizzle(__float_as_int(sc0), 0x010));
  float e0 = __expf(sc0 - mx);
  float e1 = __expf(sc1 - mx);
  float inv = 1.0f / dppsum16(e0 + e1);
  vtab[rloc][l] = vidx0;
  vtab[rloc][l + 16] = vidx1;
  wtab[rloc][l] = e0 * inv;
  wtab[rloc][l + 16] = e1 * inv;
  // gather: 128 fp32 per value row; lane reads 8 floats (2x16B) -> 512 B/row
  const float* vb = valf + (((size_t)h) << 23) + (size_t)l * 8;
  float accf[8] = {};
#pragma unroll 8
  for (int k = 0; k < 32; k++) {
    int vi = vtab[rloc][k];  // LDS broadcast (same quad, wave-synchronous)
    float wk = wtab[rloc][k];
    const float4* vp = (const float4*)(vb + (size_t)vi * 128);
    float4 v0 = vp[0];
    float4 v1 = vp[1];
    accf[0] += wk * v0.x; accf[1] += wk * v0.y;
    accf[2] += wk * v0.z; accf[3] += wk * v0.w;
    accf[4] += wk * v1.x; accf[5] += wk * v1.y;
    accf[6] += wk * v1.z; accf[7] += wk * v1.w;
  }
  f16x8 o;
#pragma unroll
  for (int j = 0; j < 8; j++) o[j] = (f16)accf[j];
  f16* op = headout + (size_t)(b * TSEQ + t) * 1024 + h * 128 + l * 8;
  *(f16x8*)op = o;
}

// ---------------------------------------------------------------------------
extern "C" void kernel_launch(void* const* d_in, const int* in_sizes, int n_in,
                              void* d_out, int out_size, void* d_ws,
                              size_t ws_size, hipStream_t stream) {
  const float* x    = (const float*)d_in[0];  // (2,2048,1024)
  const float* Wq   = (const float*)d_in[1];  // (2048,1024)
  const float* keys = (const float*)d_in[2];  // (8,256,2,128)
  const float* vals = (const float*)d_in[3];  // (8,65536,128) fp32, gathered
  const float* Wo   = (const float*)d_in[4];  // (1024,1024)
  const float* bo   = (const float*)d_in[5];  // (1024,)
  float* out = (float*)d_out;                 // (2,2048,1024) fp32
  char* ws = (char*)d_ws;
  f16*   xf   = (f16*)(ws);                         // 8 MB
  f16*   wqf  = (f16*)(ws + (size_t)(8u << 20));    // 4 MB
  f16*   wof  = (f16*)(ws + (size_t)(12u << 20));   // 2 MB
  f16*   kyf  = (f16*)(ws + (size_t)(14u << 20));   // 1 MB
  float* s1s  = (float*)(ws + (size_t)(16u << 20)); // 8 MB
  int*   s1i  = (int*)(ws + (size_t)(24u << 20));   // 8 MB
  f16*   hof  = (f16*)(ws + (size_t)(32u << 20));   // 8 MB (4096x1024)

  // 0) fp32 -> f16 for x, Wq, Wo, keys (values stay fp32)
  cvt_all<<<dim3(7680), 256, 0, stream>>>(x, Wq, Wo, keys, xf, wqf, wof, kyf);
  // 1+2 fused) Q-slice GEMM + dots + stage-1 top-32 (per (h,p) x 64-row tile)
  qdots_topk1<<<dim3(16, 64), 256, 0, stream>>>(xf, wqf, kyf, s1s, s1i);
  // 3) stage-2 top-32 + softmax + fp32 gather -> headout f16
  topk2_gather<<<dim3(32768 / 16), 256, 0, stream>>>(s1s, s1i, vals, hof);
  // 4) out = headout @ Wo^T + bo  (M=4096,N=1024,K=1024), fp32 out, BN=64
  gemm_f16<64><<<dim3(16, 32), 256, 0, stream>>>(hof, 1024, wof, 1024, bo, out,
                                                 1024, 1024, 0);
}

// Round 5
// 515.118 us; speedup vs baseline: 1.0689x; 1.0689x over previous
//
#include <hip/hip_runtime.h>

typedef unsigned int u32;
typedef unsigned long long u64;
typedef _Float16 f16;
typedef __attribute__((ext_vector_type(4))) _Float16 f16x4;
typedef __attribute__((ext_vector_type(8))) _Float16 f16x8;
typedef __attribute__((ext_vector_type(4))) float f32x4;
typedef const __attribute__((address_space(1))) void* gp_t;
typedef __attribute__((address_space(3))) void* lp_t;

#define TSEQ 2048

// monotone fp32 -> u32 map (order-preserving)
__device__ __forceinline__ u32 f2sort(float f) {
  u32 u = __float_as_uint(f);
  return u ^ ((u32)((int)u >> 31) | 0x80000000u);
}
__device__ __forceinline__ float sort2f(u32 u) {
  u ^= (u & 0x80000000u) ? 0x80000000u : 0xFFFFFFFFu;
  return __uint_as_float(u);
}

__device__ __forceinline__ void glds16(const f16* g, f16* l) {
  __builtin_amdgcn_global_load_lds((gp_t)g, (lp_t)l, 16, 0, 0);
}

// counted vmcnt wait (literal immediates only)
template <int N> __device__ __forceinline__ void waitvm() {
  if constexpr (N == 0) asm volatile("s_waitcnt vmcnt(0)" ::: "memory");
  else if constexpr (N == 3) asm volatile("s_waitcnt vmcnt(3)" ::: "memory");
  else if constexpr (N == 4) asm volatile("s_waitcnt vmcnt(4)" ::: "memory");
  else asm volatile("s_waitcnt vmcnt(5)" ::: "memory");
}
// raw barrier + scheduling fence: prevents the compiler from hoisting the
// following LDS reads above the barrier (rule #18-style hazard).
__device__ __forceinline__ void barrier_fenced() {
  __builtin_amdgcn_s_barrier();
  __builtin_amdgcn_sched_barrier(0);
}

__device__ __forceinline__ u32 umax2(u32 a, u32 b) { return a > b ? a : b; }

// max across each 16-lane DPP row via rotate-reduce (row_ror 8/4/2/1).
// All 16 lanes end with the row max; DPP-only, no LDS op on the chain.
__device__ __forceinline__ u32 dppmax16(u32 v) {
  u32 t;
  t = (u32)__builtin_amdgcn_update_dpp(0, (int)v, 0x128, 0xF, 0xF, true);
  v = v > t ? v : t;
  t = (u32)__builtin_amdgcn_update_dpp(0, (int)v, 0x124, 0xF, 0xF, true);
  v = v > t ? v : t;
  t = (u32)__builtin_amdgcn_update_dpp(0, (int)v, 0x122, 0xF, 0xF, true);
  v = v > t ? v : t;
  t = (u32)__builtin_amdgcn_update_dpp(0, (int)v, 0x121, 0xF, 0xF, true);
  v = v > t ? v : t;
  return v;
}
// sum across each 16-lane row via rotate-reduce, result in all 16 lanes
__device__ __forceinline__ float dppsum16(float v) {
  float t;
  t = __int_as_float(
      __builtin_amdgcn_update_dpp(0, __float_as_int(v), 0x128, 0xF, 0xF, true));
  v += t;
  t = __int_as_float(
      __builtin_amdgcn_update_dpp(0, __float_as_int(v), 0x124, 0xF, 0xF, true));
  v += t;
  t = __int_as_float(
      __builtin_amdgcn_update_dpp(0, __float_as_int(v), 0x122, 0xF, 0xF, true));
  v += t;
  t = __int_as_float(
      __builtin_amdgcn_update_dpp(0, __float_as_int(v), 0x121, 0xF, 0xF, true));
  v += t;
  return v;
}

// depth-4 tree max over 16 registers
__device__ __forceinline__ u32 tree16(const u32* k) {
  u32 t0 = umax2(k[0], k[1]), t1 = umax2(k[2], k[3]);
  u32 t2 = umax2(k[4], k[5]), t3 = umax2(k[6], k[7]);
  u32 t4 = umax2(k[8], k[9]), t5 = umax2(k[10], k[11]);
  u32 t6 = umax2(k[12], k[13]), t7 = umax2(k[14], k[15]);
  t0 = umax2(t0, t1); t2 = umax2(t2, t3);
  t4 = umax2(t4, t5); t6 = umax2(t6, t7);
  return umax2(umax2(t0, t2), umax2(t4, t6));
}

// ---------------------------------------------------------------------------
// fp32 -> f16: x (1048576 f4), Wq (524288), Wo (262144), keys (131072).
// values stay fp32 (gathered directly). grid = 7680 blocks exactly.
// ---------------------------------------------------------------------------
__global__ __launch_bounds__(256) void cvt_all(
    const float* __restrict__ x, const float* __restrict__ wq,
    const float* __restrict__ wo, const float* __restrict__ ky,
    f16* __restrict__ xd, f16* __restrict__ wqd, f16* __restrict__ wod,
    f16* __restrict__ kyd) {
  int g = blockIdx.x * 256 + threadIdx.x;
  const float* s;
  f16* d;
  int off;
  if (g < 1048576)      { s = x;  d = xd;  off = g; }
  else if (g < 1572864) { s = wq; d = wqd; off = g - 1048576; }
  else if (g < 1835008) { s = wo; d = wod; off = g - 1572864; }
  else                  { s = ky; d = kyd; off = g - 1835008; }
  float4 v = ((const float4*)s)[off];
  f16x4 o;
  o[0] = (f16)v.x; o[1] = (f16)v.y; o[2] = (f16)v.z; o[3] = (f16)v.w;
  ((f16x4*)d)[off] = o;
}

// ---------------------------------------------------------------------------
// f16 NT GEMM with double-buffered LDS + counted-vmcnt prefetch:
// STAGE(next) issued BEFORE compute(cur); s_waitcnt vmcnt(NLD) (own next-tile
// loads stay in flight across the raw s_barrier -> HBM latency hides under
// MFMA). Raw barriers (no compiler vmcnt(0) drain). 128xBN tile, BK=32.
// ---------------------------------------------------------------------------
template <int BN>
__global__ __launch_bounds__(256) void gemm_f16(
    const f16* __restrict__ A, int lda, const f16* __restrict__ B, int ldb,
    const float* __restrict__ bias, void* __restrict__ Cv, int ldc, int K,
    int c_f16) {
  constexpr int NJ = BN / 32;
  constexpr int NLD = (BN == 128) ? 4 : 3;  // glds per thread per tile
  __shared__ f16 As[2][128 * 32];
  __shared__ f16 Bs[2][BN * 32];
  const int tid = threadIdx.x;
  const int lane = tid & 63, wave = tid >> 6;
  const int m0 = blockIdx.y << 7, n0 = blockIdx.x * BN;
  const int c0 = wave * 128 + lane, c1 = c0 + 64;
  const int r0 = c0 >> 2, s0 = c0 & 3;
  const int r1 = c1 >> 2, s1 = c1 & 3;
  const int cB = wave * 64 + lane;  // BN=64 B-staging index
  const int rB = cB >> 2, sB = cB & 3;
  const f16* Ab = A + (size_t)m0 * lda;
  const f16* Bb = B + (size_t)n0 * ldb;
  const int fm = lane & 15, fq = lane >> 4, fk = fq << 3;
  const int wm = (wave >> 1) << 6, wn = (wave & 1) * (BN / 2);
  f32x4 acc[4][NJ] = {};
  auto stage = [&](int buf, int k0) {
    glds16(Ab + (size_t)r0 * lda + k0 + s0 * 8,
           As[buf] + (size_t)c0 * 8 - lane * 8);
    glds16(Ab + (size_t)r1 * lda + k0 + s1 * 8,
           As[buf] + (size_t)c1 * 8 - lane * 8);
    if constexpr (BN == 128) {
      glds16(Bb + (size_t)r0 * ldb + k0 + s0 * 8,
             Bs[buf] + (size_t)c0 * 8 - lane * 8);
      glds16(Bb + (size_t)r1 * ldb + k0 + s1 * 8,
             Bs[buf] + (size_t)c1 * 8 - lane * 8);
    } else {
      glds16(Bb + (size_t)rB * ldb + k0 + sB * 8,
             Bs[buf] + (size_t)cB * 8 - lane * 8);
    }
  };
  const int nt = K >> 5;
  stage(0, 0);
  for (int t = 0; t < nt; t++) {
    const int cur = t & 1;
    if (t + 1 < nt) {
      stage(cur ^ 1, (t + 1) << 5);
      waitvm<NLD>();  // own cur-tile loads done; next-tile stays in flight
    } else {
      waitvm<0>();
    }
    barrier_fenced();
    f16x8 af[4], bf[NJ];
#pragma unroll
    for (int mi = 0; mi < 4; mi++)
      af[mi] = *(const f16x8*)&As[cur][(wm + mi * 16 + fm) * 32 + fk];
#pragma unroll
    for (int nj = 0; nj < NJ; nj++)
      bf[nj] = *(const f16x8*)&Bs[cur][(wn + nj * 16 + fm) * 32 + fk];
#pragma unroll
    for (int mi = 0; mi < 4; mi++)
#pragma unroll
      for (int nj = 0; nj < NJ; nj++)
        acc[mi][nj] = __builtin_amdgcn_mfma_f32_16x16x32_f16(
            af[mi], bf[nj], acc[mi][nj], 0, 0, 0);
    barrier_fenced();  // all reads of buf[cur] done before t+2 overwrites
  }
  if (c_f16) {
    f16* C = (f16*)Cv;
#pragma unroll
    for (int mi = 0; mi < 4; mi++)
#pragma unroll
      for (int r = 0; r < 4; r++) {
        int row = m0 + wm + mi * 16 + fq * 4 + r;
        f16* cp = C + (size_t)row * ldc + n0 + wn + fm;
#pragma unroll
        for (int nj = 0; nj < NJ; nj++) cp[nj * 16] = (f16)acc[mi][nj][r];
      }
  } else {
    float* C = (float*)Cv;
    float bb[NJ];
#pragma unroll
    for (int nj = 0; nj < NJ; nj++)
      bb[nj] = bias ? bias[n0 + wn + nj * 16 + fm] : 0.f;
#pragma unroll
    for (int mi = 0; mi < 4; mi++)
#pragma unroll
      for (int r = 0; r < 4; r++) {
        int row = m0 + wm + mi * 16 + fq * 4 + r;
        float* cp = C + (size_t)row * ldc + n0 + wn + fm;
#pragma unroll
        for (int nj = 0; nj < NJ; nj++) cp[nj * 16] = acc[mi][nj][r] + bb[nj];
      }
  }
}

// ---------------------------------------------------------------------------
// Fused dots + stage-1 top-32 (round-1 structure + prefetch pipeline).
// blockIdx.x = z = h*2+p, blockIdx.y = m-tile. Wave computes 16 rows x 256
// cols; K-loop double-buffered with counted vmcnt; selection via DPP
// rotate-reduce max, rows processed in PAIRS (2 independent chains).
// ---------------------------------------------------------------------------
__global__ __launch_bounds__(256) void dots_topk1(
    const f16* __restrict__ Q,      // (4096, 2048)
    const f16* __restrict__ keysf,  // (8,256,2,128)
    float* __restrict__ s1s, int* __restrict__ s1i) {
  __shared__ f16 As[2][64 * 32];
  __shared__ f16 Bs[2][256 * 32];
  const int tid = threadIdx.x;
  const int lane = tid & 63, wave = tid >> 6;
  const int z = blockIdx.x;  // h*2+p
  const int h = z >> 1, p = z & 1;
  const int m0 = blockIdx.y << 6;
  const f16* Aq = Q + (size_t)m0 * 2048 + p * 1024 + h * 128;
  const f16* Bk = keysf + ((size_t)h * 512 + p) * 128;  // row stride 256 f16
  const int cA = wave * 64 + lane;
  const int rA = cA >> 2, sA = cA & 3;
  const int fm = lane & 15, fq = lane >> 4, fk = fq << 3;
  auto stage = [&](int buf, int k0) {
    glds16(Aq + (size_t)rA * 2048 + k0 + sA * 8,
           As[buf] + (size_t)cA * 8 - lane * 8);
#pragma unroll
    for (int c = 0; c < 4; c++) {
      int cB = (wave * 4 + c) * 64 + lane;
      int rB = cB >> 2, sB = cB & 3;
      glds16(Bk + (size_t)rB * 256 + k0 + sB * 8,
             Bs[buf] + (size_t)cB * 8 - lane * 8);
    }
  };
  f32x4 acc[16] = {};
  stage(0, 0);
  for (int t = 0; t < 4; t++) {
    const int cur = t & 1;
    if (t < 3) {
      stage(cur ^ 1, (t + 1) << 5);
      waitvm<5>();
    } else {
      waitvm<0>();
    }
    barrier_fenced();
    f16x8 af = *(const f16x8*)&As[cur][(wave * 16 + fm) * 32 + fk];
#pragma unroll
    for (int j = 0; j < 16; j++) {
      f16x8 bf = *(const f16x8*)&Bs[cur][(j * 16 + fm) * 32 + fk];
      acc[j] = __builtin_amdgcn_mfma_f32_16x16x32_f16(af, bf, acc[j], 0, 0, 0);
    }
    barrier_fenced();
  }
  // top-32 per row; quad fq handles rows m0 + wave*16 + fq*4 + r.
#pragma unroll
  for (int rp = 0; rp < 2; rp++) {
    u32 keyA[16], keyB[16];
#pragma unroll
    for (int j = 0; j < 16; j++) {
      keyA[j] = (f2sort(acc[j][2 * rp]) & ~0xFFu) | (u32)((j << 4) | fm);
      keyB[j] = (f2sort(acc[j][2 * rp + 1]) & ~0xFFu) | (u32)((j << 4) | fm);
    }
    u32 g0A = 0, g1A = 0, g0B = 0, g1B = 0;
    for (int it = 0; it < 32; it++) {
      u32 lmA = tree16(keyA);
      u32 lmB = tree16(keyB);
      u32 gmA = dppmax16(lmA);
      u32 gmB = dppmax16(lmB);
#pragma unroll
      for (int j = 0; j < 16; j++) {
        keyA[j] = (keyA[j] == gmA) ? 0u : keyA[j];
        keyB[j] = (keyB[j] == gmB) ? 0u : keyB[j];
      }
      bool sel = (fm == (it & 15));
      if (it < 16) {
        g0A = sel ? gmA : g0A;
        g0B = sel ? gmB : g0B;
      } else {
        g1A = sel ? gmA : g1A;
        g1B = sel ? gmB : g1B;
      }
    }
    int mA = m0 + wave * 16 + (fq << 2) + 2 * rp;
    int bA = mA >> 11, tA = mA & 2047;
    size_t orowA = ((((size_t)(bA * 8 + h)) * TSEQ + tA) * 2 + p) * 32;
    s1s[orowA + fm] = sort2f(g0A & ~0xFFu);
    s1s[orowA + fm + 16] = sort2f(g1A & ~0xFFu);
    s1i[orowA + fm] = (int)(g0A & 0xFFu);  // n = (slot<<4)|lane
    s1i[orowA + fm + 16] = (int)(g1A & 0xFFu);
    int mB = mA + 1;
    int bB = mB >> 11, tB = mB & 2047;
    size_t orowB = ((((size_t)(bB * 8 + h)) * TSEQ + tB) * 2 + p) * 32;
    s1s[orowB + fm] = sort2f(g0B & ~0xFFu);
    s1s[orowB + fm + 16] = sort2f(g1B & ~0xFFu);
    s1i[orowB + fm] = (int)(g0B & 0xFFu);
    s1i[orowB + fm + 16] = (int)(g1B & 0xFFu);
  }
}

// ---------------------------------------------------------------------------
// Stage-2: combine halves, top-32 of 32x32 sum grid via dominance frontier
// ((i+1)(j+1)<=32 -> 119 candidates), DPP selection, softmax, fp32 value
// gather straight from the input table (~L3-resident), weighted sum -> f16.
// ---------------------------------------------------------------------------
__global__ __launch_bounds__(256) void topk2_gather(
    const float* __restrict__ s1s, const int* __restrict__ s1i,
    const float* __restrict__ valf, f16* __restrict__ headout) {
  __shared__ unsigned short cand[128];  // (i<<5)|j, 0xFFFF = pad
  __shared__ float s0sh[16][32];
  __shared__ float s1sh[16][32];
  __shared__ int i0sh[16][32];
  __shared__ int i1sh[16][32];
  __shared__ int vtab[16][32];
  __shared__ float wtab[16][32];
  const int tid = threadIdx.x;
  if (tid < 128) {
    int c = tid;
    unsigned short enc = 0xFFFF;
    if (c < 119) {
      int rem = c, i = 0;
      for (i = 0; i < 32; i++) {
        int cnt = 32 / (i + 1);
        if (rem < cnt) break;
        rem -= cnt;
      }
      enc = (unsigned short)((i << 5) | rem);
    }
    cand[tid] = enc;
  }
  const int rloc = tid >> 4;
  const int l = tid & 15;
  const int row = blockIdx.x * 16 + rloc;  // (b,h,t)
  const int b = row >> 14;
  const int h = (row >> 11) & 7;
  const int t = row & 2047;
  const int tt = t >> 1, p = t & 1;
  size_t rbase = (size_t)(b * 8 + h) * TSEQ;
  size_t base0 = ((rbase + tt) * 2 + p) * 32;
  size_t base1 = ((rbase + tt + 1024) * 2 + p) * 32;
  s0sh[rloc][l] = s1s[base0 + l];
  s0sh[rloc][l + 16] = s1s[base0 + l + 16];
  s1sh[rloc][l] = s1s[base1 + l];
  s1sh[rloc][l + 16] = s1s[base1 + l + 16];
  i0sh[rloc][l] = s1i[base0 + l];
  i0sh[rloc][l + 16] = s1i[base0 + l + 16];
  i1sh[rloc][l] = s1i[base1 + l];
  i1sh[rloc][l + 16] = s1i[base1 + l + 16];
  __syncthreads();
  u32 key[8];
#pragma unroll
  for (int s = 0; s < 8; s++) {
    int c = l + 16 * s;  // == (s<<4)|l
    unsigned short e = cand[c];
    u32 kk = 0u;
    if (e != 0xFFFF) {
      float v = s0sh[rloc][e >> 5] + s1sh[rloc][e & 31];
      kk = (f2sort(v) & ~0xFFu) | (u32)c;
    }
    key[s] = kk;
  }
  u32 g0 = 0, g1 = 0;
  for (int it = 0; it < 32; it++) {
    // depth-3 tree max over the 8 local keys
    u32 t0 = umax2(key[0], key[1]), t1 = umax2(key[2], key[3]);
    u32 t2 = umax2(key[4], key[5]), t3 = umax2(key[6], key[7]);
    u32 lm = umax2(umax2(t0, t1), umax2(t2, t3));
    u32 gm = dppmax16(lm);
#pragma unroll
    for (int s = 0; s < 8; s++) key[s] = (key[s] == gm) ? 0u : key[s];
    bool sel = (l == (it & 15));
    if (it < 16) g0 = sel ? gm : g0;
    else         g1 = sel ? gm : g1;
  }
  // decode winners (lane l holds winners l and l+16, descending order)
  float sc0 = sort2f(g0 & ~0xFFu);
  float sc1 = sort2f(g1 & ~0xFFu);
  unsigned short e0c = cand[g0 & 0xFFu];
  unsigned short e1c = cand[g1 & 0xFFu];
  int vidx0 = i0sh[rloc][e0c >> 5] * 256 + i1sh[rloc][e0c & 31];
  int vidx1 = i0sh[rloc][e1c >> 5] * 256 + i1sh[rloc][e1c & 31];
  // softmax: winner 0 (group lane 0) is the max
  float mx = __int_as_float(
      __builtin_amdgcn_ds_swizzle(__float_as_int(sc0), 0x010));
  float e0 = __expf(sc0 - mx);
  float e1 = __expf(sc1 - mx);
  float inv = 1.0f / dppsum16(e0 + e1);
  vtab[rloc][l] = vidx0;
  vtab[rloc][l + 16] = vidx1;
  wtab[rloc][l] = e0 * inv;
  wtab[rloc][l + 16] = e1 * inv;
  // gather: 128 fp32 per value row; lane reads 8 floats (2x16B) -> 512 B/row
  const float* vb = valf + (((size_t)h) << 23) + (size_t)l * 8;
  float accf[8] = {};
#pragma unroll 8
  for (int k = 0; k < 32; k++) {
    int vi = vtab[rloc][k];  // LDS broadcast (same quad, wave-synchronous)
    float wk = wtab[rloc][k];
    const float4* vp = (const float4*)(vb + (size_t)vi * 128);
    float4 v0 = vp[0];
    float4 v1 = vp[1];
    accf[0] += wk * v0.x; accf[1] += wk * v0.y;
    accf[2] += wk * v0.z; accf[3] += wk * v0.w;
    accf[4] += wk * v1.x; accf[5] += wk * v1.y;
    accf[6] += wk * v1.z; accf[7] += wk * v1.w;
  }
  f16x8 o;
#pragma unroll
  for (int j = 0; j < 8; j++) o[j] = (f16)accf[j];
  f16* op = headout + (size_t)(b * TSEQ + t) * 1024 + h * 128 + l * 8;
  *(f16x8*)op = o;
}

// ---------------------------------------------------------------------------
extern "C" void kernel_launch(void* const* d_in, const int* in_sizes, int n_in,
                              void* d_out, int out_size, void* d_ws,
                              size_t ws_size, hipStream_t stream) {
  const float* x    = (const float*)d_in[0];  // (2,2048,1024)
  const float* Wq   = (const float*)d_in[1];  // (2048,1024)
  const float* keys = (const float*)d_in[2];  // (8,256,2,128)
  const float* vals = (const float*)d_in[3];  // (8,65536,128) fp32, gathered
  const float* Wo   = (const float*)d_in[4];  // (1024,1024)
  const float* bo   = (const float*)d_in[5];  // (1024,)
  float* out = (float*)d_out;                 // (2,2048,1024) fp32
  char* ws = (char*)d_ws;
  f16*   xf   = (f16*)(ws);                         // 8 MB
  f16*   wqf  = (f16*)(ws + (size_t)(8u << 20));    // 4 MB
  f16*   wof  = (f16*)(ws + (size_t)(12u << 20));   // 2 MB
  f16*   kyf  = (f16*)(ws + (size_t)(14u << 20));   // 1 MB
  f16*   Qf   = (f16*)(ws + (size_t)(16u << 20));   // 16 MB (4096x2048)
  float* s1s  = (float*)(ws + (size_t)(32u << 20)); // 8 MB
  int*   s1i  = (int*)(ws + (size_t)(40u << 20));   // 8 MB
  f16*   hof  = (f16*)(ws + (size_t)(48u << 20));   // 8 MB (4096x1024)

  // 0) fp32 -> f16 for x, Wq, Wo, keys (values stay fp32)
  cvt_all<<<dim3(7680), 256, 0, stream>>>(x, Wq, Wo, keys, xf, wqf, wof, kyf);
  // 1) Q = x @ Wq^T  (M=4096,N=2048,K=1024), f16 out
  gemm_f16<128><<<dim3(16, 32), 256, 0, stream>>>(xf, 1024, wqf, 1024, nullptr,
                                                  Qf, 2048, 1024, 1);
  // 2) dots + stage-1 top-32 fused (per (h,p): M=4096,N=256,K=128)
  dots_topk1<<<dim3(16, 64), 256, 0, stream>>>(Qf, kyf, s1s, s1i);
  // 3) stage-2 top-32 + softmax + fp32 gather -> headout f16
  topk2_gather<<<dim3(32768 / 16), 256, 0, stream>>>(s1s, s1i, vals, hof);
  // 4) out = headout @ Wo^T + bo  (M=4096,N=1024,K=1024), fp32 out, BN=64
  gemm_f16<64><<<dim3(16, 32), 256, 0, stream>>>(hof, 1024, wof, 1024, bo, out,
                                                 1024, 1024, 0);
}

// Round 6
// 514.308 us; speedup vs baseline: 1.0706x; 1.0016x over previous
//
#include <hip/hip_runtime.h>

typedef unsigned int u32;
typedef unsigned long long u64;
typedef _Float16 f16;
typedef __attribute__((ext_vector_type(4))) _Float16 f16x4;
typedef __attribute__((ext_vector_type(8))) _Float16 f16x8;
typedef __attribute__((ext_vector_type(4))) float f32x4;
typedef const __attribute__((address_space(1))) void* gp_t;
typedef __attribute__((address_space(3))) void* lp_t;

#define TSEQ 2048

// monotone fp32 -> u32 map (order-preserving)
__device__ __forceinline__ u32 f2sort(float f) {
  u32 u = __float_as_uint(f);
  return u ^ ((u32)((int)u >> 31) | 0x80000000u);
}
__device__ __forceinline__ float sort2f(u32 u) {
  u ^= (u & 0x80000000u) ? 0x80000000u : 0xFFFFFFFFu;
  return __uint_as_float(u);
}

__device__ __forceinline__ void glds16(const f16* g, f16* l) {
  __builtin_amdgcn_global_load_lds((gp_t)g, (lp_t)l, 16, 0, 0);
}

// counted vmcnt wait (literal immediates only)
template <int N> __device__ __forceinline__ void waitvm() {
  if constexpr (N == 0) asm volatile("s_waitcnt vmcnt(0)" ::: "memory");
  else if constexpr (N == 3) asm volatile("s_waitcnt vmcnt(3)" ::: "memory");
  else if constexpr (N == 4) asm volatile("s_waitcnt vmcnt(4)" ::: "memory");
  else asm volatile("s_waitcnt vmcnt(5)" ::: "memory");
}
// raw barrier + scheduling fence: prevents the compiler from hoisting the
// following LDS reads above the barrier (rule #18-style hazard).
__device__ __forceinline__ void barrier_fenced() {
  __builtin_amdgcn_s_barrier();
  __builtin_amdgcn_sched_barrier(0);
}

// XCD-aware bijective chunked swizzle (nwg % 8 == 0 at all call sites):
// hardware round-robin (bid -> XCD bid%8) then picks contiguous logical
// chunks of nwg/8 per XCD.
__device__ __forceinline__ int xcd_swz(int bid, int nwg) {
  return (bid & 7) * (nwg >> 3) + (bid >> 3);
}

__device__ __forceinline__ u32 umax2(u32 a, u32 b) { return a > b ? a : b; }

// max across each 16-lane DPP row via rotate-reduce (row_ror 8/4/2/1).
// All 16 lanes end with the row max; DPP-only, no LDS op on the chain.
__device__ __forceinline__ u32 dppmax16(u32 v) {
  u32 t;
  t = (u32)__builtin_amdgcn_update_dpp(0, (int)v, 0x128, 0xF, 0xF, true);
  v = v > t ? v : t;
  t = (u32)__builtin_amdgcn_update_dpp(0, (int)v, 0x124, 0xF, 0xF, true);
  v = v > t ? v : t;
  t = (u32)__builtin_amdgcn_update_dpp(0, (int)v, 0x122, 0xF, 0xF, true);
  v = v > t ? v : t;
  t = (u32)__builtin_amdgcn_update_dpp(0, (int)v, 0x121, 0xF, 0xF, true);
  v = v > t ? v : t;
  return v;
}
// sum across each 16-lane row via rotate-reduce, result in all 16 lanes
__device__ __forceinline__ float dppsum16(float v) {
  float t;
  t = __int_as_float(
      __builtin_amdgcn_update_dpp(0, __float_as_int(v), 0x128, 0xF, 0xF, true));
  v += t;
  t = __int_as_float(
      __builtin_amdgcn_update_dpp(0, __float_as_int(v), 0x124, 0xF, 0xF, true));
  v += t;
  t = __int_as_float(
      __builtin_amdgcn_update_dpp(0, __float_as_int(v), 0x122, 0xF, 0xF, true));
  v += t;
  t = __int_as_float(
      __builtin_amdgcn_update_dpp(0, __float_as_int(v), 0x121, 0xF, 0xF, true));
  v += t;
  return v;
}

// depth-4 tree max over 16 registers
__device__ __forceinline__ u32 tree16(const u32* k) {
  u32 t0 = umax2(k[0], k[1]), t1 = umax2(k[2], k[3]);
  u32 t2 = umax2(k[4], k[5]), t3 = umax2(k[6], k[7]);
  u32 t4 = umax2(k[8], k[9]), t5 = umax2(k[10], k[11]);
  u32 t6 = umax2(k[12], k[13]), t7 = umax2(k[14], k[15]);
  t0 = umax2(t0, t1); t2 = umax2(t2, t3);
  t4 = umax2(t4, t5); t6 = umax2(t6, t7);
  return umax2(umax2(t0, t2), umax2(t4, t6));
}

// ---------------------------------------------------------------------------
// fp32 -> f16: x (1048576 f4), Wq (524288), Wo (262144), keys (131072).
// values stay fp32 (gathered directly). grid = 7680 blocks exactly.
// ---------------------------------------------------------------------------
__global__ __launch_bounds__(256) void cvt_all(
    const float* __restrict__ x, const float* __restrict__ wq,
    const float* __restrict__ wo, const float* __restrict__ ky,
    f16* __restrict__ xd, f16* __restrict__ wqd, f16* __restrict__ wod,
    f16* __restrict__ kyd) {
  int g = blockIdx.x * 256 + threadIdx.x;
  const float* s;
  f16* d;
  int off;
  if (g < 1048576)      { s = x;  d = xd;  off = g; }
  else if (g < 1572864) { s = wq; d = wqd; off = g - 1048576; }
  else if (g < 1835008) { s = wo; d = wod; off = g - 1572864; }
  else                  { s = ky; d = kyd; off = g - 1835008; }
  float4 v = ((const float4*)s)[off];
  f16x4 o;
  o[0] = (f16)v.x; o[1] = (f16)v.y; o[2] = (f16)v.z; o[3] = (f16)v.w;
  ((f16x4*)d)[off] = o;
}

// ---------------------------------------------------------------------------
// f16 NT GEMM with double-buffered LDS + counted-vmcnt prefetch + XCD-aware
// block swizzle + setprio around the MFMA cluster. 128xBN tile, BK=32.
// ---------------------------------------------------------------------------
template <int BN>
__global__ __launch_bounds__(256) void gemm_f16(
    const f16* __restrict__ A, int lda, const f16* __restrict__ B, int ldb,
    const float* __restrict__ bias, void* __restrict__ Cv, int ldc, int K,
    int c_f16) {
  constexpr int NJ = BN / 32;
  constexpr int NLD = (BN == 128) ? 4 : 3;  // glds per thread per tile
  __shared__ f16 As[2][128 * 32];
  __shared__ f16 Bs[2][BN * 32];
  const int tid = threadIdx.x;
  const int lane = tid & 63, wave = tid >> 6;
  // XCD swizzle: n-major logical flat; each XCD gets a contiguous chunk.
  const int gx = gridDim.x, nwg = gx * gridDim.y;
  const int swz = xcd_swz(blockIdx.x + gx * blockIdx.y, nwg);
  const int bx = swz % gx, by = swz / gx;
  const int m0 = by << 7, n0 = bx * BN;
  const int c0 = wave * 128 + lane, c1 = c0 + 64;
  const int r0 = c0 >> 2, s0 = c0 & 3;
  const int r1 = c1 >> 2, s1 = c1 & 3;
  const int cB = wave * 64 + lane;  // BN=64 B-staging index
  const int rB = cB >> 2, sB = cB & 3;
  const f16* Ab = A + (size_t)m0 * lda;
  const f16* Bb = B + (size_t)n0 * ldb;
  const int fm = lane & 15, fq = lane >> 4, fk = fq << 3;
  const int wm = (wave >> 1) << 6, wn = (wave & 1) * (BN / 2);
  f32x4 acc[4][NJ] = {};
  auto stage = [&](int buf, int k0) {
    glds16(Ab + (size_t)r0 * lda + k0 + s0 * 8,
           As[buf] + (size_t)c0 * 8 - lane * 8);
    glds16(Ab + (size_t)r1 * lda + k0 + s1 * 8,
           As[buf] + (size_t)c1 * 8 - lane * 8);
    if constexpr (BN == 128) {
      glds16(Bb + (size_t)r0 * ldb + k0 + s0 * 8,
             Bs[buf] + (size_t)c0 * 8 - lane * 8);
      glds16(Bb + (size_t)r1 * ldb + k0 + s1 * 8,
             Bs[buf] + (size_t)c1 * 8 - lane * 8);
    } else {
      glds16(Bb + (size_t)rB * ldb + k0 + sB * 8,
             Bs[buf] + (size_t)cB * 8 - lane * 8);
    }
  };
  const int nt = K >> 5;
  stage(0, 0);
  for (int t = 0; t < nt; t++) {
    const int cur = t & 1;
    if (t + 1 < nt) {
      stage(cur ^ 1, (t + 1) << 5);
      waitvm<NLD>();  // own cur-tile loads done; next-tile stays in flight
    } else {
      waitvm<0>();
    }
    barrier_fenced();
    f16x8 af[4], bf[NJ];
#pragma unroll
    for (int mi = 0; mi < 4; mi++)
      af[mi] = *(const f16x8*)&As[cur][(wm + mi * 16 + fm) * 32 + fk];
#pragma unroll
    for (int nj = 0; nj < NJ; nj++)
      bf[nj] = *(const f16x8*)&Bs[cur][(wn + nj * 16 + fm) * 32 + fk];
    __builtin_amdgcn_s_setprio(1);
#pragma unroll
    for (int mi = 0; mi < 4; mi++)
#pragma unroll
      for (int nj = 0; nj < NJ; nj++)
        acc[mi][nj] = __builtin_amdgcn_mfma_f32_16x16x32_f16(
            af[mi], bf[nj], acc[mi][nj], 0, 0, 0);
    __builtin_amdgcn_s_setprio(0);
    barrier_fenced();  // all reads of buf[cur] done before t+2 overwrites
  }
  if (c_f16) {
    f16* C = (f16*)Cv;
#pragma unroll
    for (int mi = 0; mi < 4; mi++)
#pragma unroll
      for (int r = 0; r < 4; r++) {
        int row = m0 + wm + mi * 16 + fq * 4 + r;
        f16* cp = C + (size_t)row * ldc + n0 + wn + fm;
#pragma unroll
        for (int nj = 0; nj < NJ; nj++) cp[nj * 16] = (f16)acc[mi][nj][r];
      }
  } else {
    float* C = (float*)Cv;
    float bb[NJ];
#pragma unroll
    for (int nj = 0; nj < NJ; nj++)
      bb[nj] = bias ? bias[n0 + wn + nj * 16 + fm] : 0.f;
#pragma unroll
    for (int mi = 0; mi < 4; mi++)
#pragma unroll
      for (int r = 0; r < 4; r++) {
        int row = m0 + wm + mi * 16 + fq * 4 + r;
        float* cp = C + (size_t)row * ldc + n0 + wn + fm;
#pragma unroll
        for (int nj = 0; nj < NJ; nj++) cp[nj * 16] = acc[mi][nj][r] + bb[nj];
      }
  }
}

// ---------------------------------------------------------------------------
// Fused dots + stage-1 top-32 (dbuf + counted vmcnt + z-major XCD swizzle).
// Wave computes 16 rows x 256 cols; selection via DPP rotate-reduce max,
// rows processed in PAIRS (2 independent chains). Output: PACKED u32 keys
// (score top-24 | idx-8) -- the sort key IS the record.
// ---------------------------------------------------------------------------
__global__ __launch_bounds__(256) void dots_topk1(
    const f16* __restrict__ Q,      // (4096, 2048)
    const f16* __restrict__ keysf,  // (8,256,2,128)
    u32* __restrict__ s1p) {
  __shared__ f16 As[2][64 * 32];
  __shared__ f16 Bs[2][256 * 32];
  const int tid = threadIdx.x;
  const int lane = tid & 63, wave = tid >> 6;
  // z-major logical id + XCD chunking: each XCD works 2 consecutive z
  // (two 64 KB key slices stay in its L2).
  const int swz = xcd_swz(blockIdx.x + 16 * blockIdx.y, 1024);
  const int z = swz >> 6;       // h*2+p
  const int h = z >> 1, p = z & 1;
  const int m0 = (swz & 63) << 6;
  const f16* Aq = Q + (size_t)m0 * 2048 + p * 1024 + h * 128;
  const f16* Bk = keysf + ((size_t)h * 512 + p) * 128;  // row stride 256 f16
  const int cA = wave * 64 + lane;
  const int rA = cA >> 2, sA = cA & 3;
  const int fm = lane & 15, fq = lane >> 4, fk = fq << 3;
  auto stage = [&](int buf, int k0) {
    glds16(Aq + (size_t)rA * 2048 + k0 + sA * 8,
           As[buf] + (size_t)cA * 8 - lane * 8);
#pragma unroll
    for (int c = 0; c < 4; c++) {
      int cB = (wave * 4 + c) * 64 + lane;
      int rB = cB >> 2, sB = cB & 3;
      glds16(Bk + (size_t)rB * 256 + k0 + sB * 8,
             Bs[buf] + (size_t)cB * 8 - lane * 8);
    }
  };
  f32x4 acc[16] = {};
  stage(0, 0);
  for (int t = 0; t < 4; t++) {
    const int cur = t & 1;
    if (t < 3) {
      stage(cur ^ 1, (t + 1) << 5);
      waitvm<5>();
    } else {
      waitvm<0>();
    }
    barrier_fenced();
    f16x8 af = *(const f16x8*)&As[cur][(wave * 16 + fm) * 32 + fk];
    __builtin_amdgcn_s_setprio(1);
#pragma unroll
    for (int j = 0; j < 16; j++) {
      f16x8 bf = *(const f16x8*)&Bs[cur][(j * 16 + fm) * 32 + fk];
      acc[j] = __builtin_amdgcn_mfma_f32_16x16x32_f16(af, bf, acc[j], 0, 0, 0);
    }
    __builtin_amdgcn_s_setprio(0);
    barrier_fenced();
  }
  // top-32 per row; quad fq handles rows m0 + wave*16 + fq*4 + r.
#pragma unroll
  for (int rp = 0; rp < 2; rp++) {
    u32 keyA[16], keyB[16];
#pragma unroll
    for (int j = 0; j < 16; j++) {
      keyA[j] = (f2sort(acc[j][2 * rp]) & ~0xFFu) | (u32)((j << 4) | fm);
      keyB[j] = (f2sort(acc[j][2 * rp + 1]) & ~0xFFu) | (u32)((j << 4) | fm);
    }
    u32 g0A = 0, g1A = 0, g0B = 0, g1B = 0;
    for (int it = 0; it < 32; it++) {
      u32 lmA = tree16(keyA);
      u32 lmB = tree16(keyB);
      u32 gmA = dppmax16(lmA);
      u32 gmB = dppmax16(lmB);
#pragma unroll
      for (int j = 0; j < 16; j++) {
        keyA[j] = (keyA[j] == gmA) ? 0u : keyA[j];
        keyB[j] = (keyB[j] == gmB) ? 0u : keyB[j];
      }
      bool sel = (fm == (it & 15));
      if (it < 16) {
        g0A = sel ? gmA : g0A;
        g0B = sel ? gmB : g0B;
      } else {
        g1A = sel ? gmA : g1A;
        g1B = sel ? gmB : g1B;
      }
    }
    int mA = m0 + wave * 16 + (fq << 2) + 2 * rp;
    int bA = mA >> 11, tA = mA & 2047;
    size_t orowA = ((((size_t)(bA * 8 + h)) * TSEQ + tA) * 2 + p) * 32;
    s1p[orowA + fm] = g0A;
    s1p[orowA + fm + 16] = g1A;
    int mB = mA + 1;
    int bB = mB >> 11, tB = mB & 2047;
    size_t orowB = ((((size_t)(bB * 8 + h)) * TSEQ + tB) * 2 + p) * 32;
    s1p[orowB + fm] = g0B;
    s1p[orowB + fm + 16] = g1B;
  }
}

// ---------------------------------------------------------------------------
// Stage-2: combine halves, top-32 of 32x32 sum grid via dominance frontier
// ((i+1)(j+1)<=32 -> 119 candidates), DPP selection, softmax, fp32 value
// gather straight from the input table, weighted sum -> f16.
// Gather phase: 32 lanes/row x 2 passes (each lane covers half the k-range;
// partial sums combined via ds_swizzle xor-16) -> per-lane load chain halved.
// ---------------------------------------------------------------------------
__global__ __launch_bounds__(256) void topk2_gather(
    const u32* __restrict__ s1p, const float* __restrict__ valf,
    f16* __restrict__ headout) {
  __shared__ unsigned short cand[128];  // (i<<5)|j, 0xFFFF = pad
  __shared__ u32 k0sh[16][32];
  __shared__ u32 k1sh[16][32];
  __shared__ int vtab[16][32];
  __shared__ float wtab[16][32];
  const int tid = threadIdx.x;
  if (tid < 128) {
    int c = tid;
    unsigned short enc = 0xFFFF;
    if (c < 119) {
      int rem = c, i = 0;
      for (i = 0; i < 32; i++) {
        int cnt = 32 / (i + 1);
        if (rem < cnt) break;
        rem -= cnt;
      }
      enc = (unsigned short)((i << 5) | rem);
    }
    cand[tid] = enc;
  }
  const int rloc = tid >> 4;
  const int l = tid & 15;
  {
    const int row = blockIdx.x * 16 + rloc;  // (b,h,t)
    const int b = row >> 14;
    const int h = (row >> 11) & 7;
    const int t = row & 2047;
    const int tt = t >> 1, p = t & 1;
    size_t rbase = (size_t)(b * 8 + h) * TSEQ;
    size_t base0 = ((rbase + tt) * 2 + p) * 32;
    size_t base1 = ((rbase + tt + 1024) * 2 + p) * 32;
    k0sh[rloc][l] = s1p[base0 + l];
    k0sh[rloc][l + 16] = s1p[base0 + l + 16];
    k1sh[rloc][l] = s1p[base1 + l];
    k1sh[rloc][l + 16] = s1p[base1 + l + 16];
  }
  __syncthreads();
  u32 key[8];
#pragma unroll
  for (int s = 0; s < 8; s++) {
    int c = l + 16 * s;  // == (s<<4)|l
    unsigned short e = cand[c];
    u32 kk = 0u;
    if (e != 0xFFFF) {
      float v = sort2f(k0sh[rloc][e >> 5] & ~0xFFu) +
                sort2f(k1sh[rloc][e & 31] & ~0xFFu);
      kk = (f2sort(v) & ~0xFFu) | (u32)c;
    }
    key[s] = kk;
  }
  u32 g0 = 0, g1 = 0;
  for (int it = 0; it < 32; it++) {
    // depth-3 tree max over the 8 local keys
    u32 t0 = umax2(key[0], key[1]), t1 = umax2(key[2], key[3]);
    u32 t2 = umax2(key[4], key[5]), t3 = umax2(key[6], key[7]);
    u32 lm = umax2(umax2(t0, t1), umax2(t2, t3));
    u32 gm = dppmax16(lm);
#pragma unroll
    for (int s = 0; s < 8; s++) key[s] = (key[s] == gm) ? 0u : key[s];
    bool sel = (l == (it & 15));
    if (it < 16) g0 = sel ? gm : g0;
    else         g1 = sel ? gm : g1;
  }
  // decode winners (lane l holds winners l and l+16, descending order)
  float sc0 = sort2f(g0 & ~0xFFu);
  float sc1 = sort2f(g1 & ~0xFFu);
  unsigned short e0c = cand[g0 & 0xFFu];
  unsigned short e1c = cand[g1 & 0xFFu];
  int vidx0 = (int)(k0sh[rloc][e0c >> 5] & 0xFFu) * 256 +
              (int)(k1sh[rloc][e0c & 31] & 0xFFu);
  int vidx1 = (int)(k0sh[rloc][e1c >> 5] & 0xFFu) * 256 +
              (int)(k1sh[rloc][e1c & 31] & 0xFFu);
  // softmax: winner 0 (group lane 0) is the max
  float mx = __int_as_float(
      __builtin_amdgcn_ds_swizzle(__float_as_int(sc0), 0x010));
  float e0 = __expf(sc0 - mx);
  float e1 = __expf(sc1 - mx);
  float inv = 1.0f / dppsum16(e0 + e1);
  vtab[rloc][l] = vidx0;
  vtab[rloc][l + 16] = vidx1;
  wtab[rloc][l] = e0 * inv;
  wtab[rloc][l + 16] = e1 * inv;
  __syncthreads();  // vtab/wtab of all quads visible to all waves
  // gather: 32 lanes per row, 2 passes of 8 rows. lane covers cols l4*8..+7,
  // k-range sub*16..+15; partner lanes (xor 16) hold the other k-half.
  const int l4 = tid & 15;
  const int sub = (tid >> 4) & 1;
#pragma unroll
  for (int pass = 0; pass < 2; pass++) {
    const int rg = pass * 8 + (tid >> 5);
    const int row = blockIdx.x * 16 + rg;
    const int b = row >> 14;
    const int h = (row >> 11) & 7;
    const int t = row & 2047;
    const float* vb = valf + (((size_t)h) << 23) + (size_t)l4 * 8;
    float accf[8] = {};
    const int kbase = sub * 16;
#pragma unroll 8
    for (int k = 0; k < 16; k++) {
      int vi = vtab[rg][kbase + k];
      float wk = wtab[rg][kbase + k];
      const float4* vp = (const float4*)(vb + (size_t)vi * 128);
      float4 v0 = vp[0];
      float4 v1 = vp[1];
      accf[0] += wk * v0.x; accf[1] += wk * v0.y;
      accf[2] += wk * v0.z; accf[3] += wk * v0.w;
      accf[4] += wk * v1.x; accf[5] += wk * v1.y;
      accf[6] += wk * v1.z; accf[7] += wk * v1.w;
    }
    // combine k-halves: lane <-> lane^16 (ds_swizzle xor-16, within 32-half)
#pragma unroll
    for (int j = 0; j < 8; j++)
      accf[j] += __int_as_float(
          __builtin_amdgcn_ds_swizzle(__float_as_int(accf[j]), 0x401F));
    if (sub == 0) {
      f16x8 o;
#pragma unroll
      for (int j = 0; j < 8; j++) o[j] = (f16)accf[j];
      f16* op = headout + (size_t)(b * TSEQ + t) * 1024 + h * 128 + l4 * 8;
      *(f16x8*)op = o;
    }
  }
}

// ---------------------------------------------------------------------------
extern "C" void kernel_launch(void* const* d_in, const int* in_sizes, int n_in,
                              void* d_out, int out_size, void* d_ws,
                              size_t ws_size, hipStream_t stream) {
  const float* x    = (const float*)d_in[0];  // (2,2048,1024)
  const float* Wq   = (const float*)d_in[1];  // (2048,1024)
  const float* keys = (const float*)d_in[2];  // (8,256,2,128)
  const float* vals = (const float*)d_in[3];  // (8,65536,128) fp32, gathered
  const float* Wo   = (const float*)d_in[4];  // (1024,1024)
  const float* bo   = (const float*)d_in[5];  // (1024,)
  float* out = (float*)d_out;                 // (2,2048,1024) fp32
  char* ws = (char*)d_ws;
  f16*   xf   = (f16*)(ws);                         // 8 MB
  f16*   wqf  = (f16*)(ws + (size_t)(8u << 20));    // 4 MB
  f16*   wof  = (f16*)(ws + (size_t)(12u << 20));   // 2 MB
  f16*   kyf  = (f16*)(ws + (size_t)(14u << 20));   // 1 MB
  f16*   Qf   = (f16*)(ws + (size_t)(16u << 20));   // 16 MB (4096x2048)
  u32*   s1p  = (u32*)(ws + (size_t)(32u << 20));   // 8 MB packed keys
  f16*   hof  = (f16*)(ws + (size_t)(40u << 20));   // 8 MB (4096x1024)

  // 0) fp32 -> f16 for x, Wq, Wo, keys (values stay fp32)
  cvt_all<<<dim3(7680), 256, 0, stream>>>(x, Wq, Wo, keys, xf, wqf, wof, kyf);
  // 1) Q = x @ Wq^T  (M=4096,N=2048,K=1024), f16 out
  gemm_f16<128><<<dim3(16, 32), 256, 0, stream>>>(xf, 1024, wqf, 1024, nullptr,
                                                  Qf, 2048, 1024, 1);
  // 2) dots + stage-1 top-32 fused (per (h,p): M=4096,N=256,K=128)
  dots_topk1<<<dim3(16, 64), 256, 0, stream>>>(Qf, kyf, s1p);
  // 3) stage-2 top-32 + softmax + fp32 gather -> headout f16
  topk2_gather<<<dim3(32768 / 16), 256, 0, stream>>>(s1p, vals, hof);
  // 4) out = headout @ Wo^T + bo  (M=4096,N=1024,K=1024), fp32 out, BN=64
  gemm_f16<64><<<dim3(16, 32), 256, 0, stream>>>(hof, 1024, wof, 1024, bo, out,
                                                 1024, 1024, 0);
}